// Round 5
// baseline (541.805 us; speedup 1.0000x reference)
//
#include <hip/hip_runtime.h>
#include <cstdint>
#include <cstddef>

typedef short short8 __attribute__((ext_vector_type(8)));
typedef short short4v __attribute__((ext_vector_type(4)));
typedef float floatx4 __attribute__((ext_vector_type(4)));
typedef unsigned short ushort4v __attribute__((ext_vector_type(4)));

constexpr int B_ = 2, S_ = 2048, H_ = 1024, NH_ = 16, DH_ = 64;
constexpr int M_ = B_ * S_;   // 4096
constexpr int K_ = H_;        // 1024

__device__ __forceinline__ unsigned short f2bf(float f) {
  unsigned u = __float_as_uint(f);
  u += 0x7fffu + ((u >> 16) & 1u);   // RNE
  return (unsigned short)(u >> 16);
}

// pack two floats to bf16x2 (round-half-up; bias cancels in p/sum(p))
__device__ __forceinline__ unsigned pack2bf(float a, float b) {
  unsigned ua = (__float_as_uint(a) + 0x8000u) >> 16;
  unsigned ub = (__float_as_uint(b) + 0x8000u) & 0xffff0000u;
  return ua | ub;
}

// ---------------- fp32 -> bf16 conversion ----------------
__global__ __launch_bounds__(256) void cvt_bf16(const float* __restrict__ in,
                                                unsigned short* __restrict__ out, int n) {
  int i = (blockIdx.x * blockDim.x + threadIdx.x) * 4;
  if (i >= n) return;
  float4 v = *reinterpret_cast<const float4*>(in + i);
  ushort4v o;
  o.x = f2bf(v.x); o.y = f2bf(v.y); o.z = f2bf(v.z); o.w = f2bf(v.w);
  *reinterpret_cast<ushort4v*>(out + i) = o;
}

// ---------------- local mask -> bitmask (1 bit/key) ----------------
__global__ __launch_bounds__(256) void build_bitmask(const int* __restrict__ lm,
                                                     unsigned long long* __restrict__ bm) {
  int word = blockIdx.x * 4 + (threadIdx.x >> 6);
  int lane = threadIdx.x & 63;
  unsigned long long bits = __ballot(lm[(size_t)word * 64 + lane] != 0);
  if (lane == 0) bm[word] = bits;
}

// ---------------- exp(amask) table [B,S] ----------------
__global__ __launch_bounds__(256) void build_eam(const float* __restrict__ am,
                                                 float* __restrict__ ea) {
  int i = blockIdx.x * 256 + threadIdx.x;
  ea[i] = __expf(am[i]);
}

// ---------------- async global->LDS 16B ----------------
typedef __attribute__((address_space(1))) const void gvoid;
typedef __attribute__((address_space(3))) void lvoid;
__device__ __forceinline__ void async16(const unsigned short* gp, unsigned short* lp) {
  __builtin_amdgcn_global_load_lds((gvoid*)gp, (lvoid*)lp, 16, 0, 0);
}

// ---------------- QKV projection GEMM (unchanged, verified) ----------------
__global__ __launch_bounds__(256) void gemm_qkv(
    const unsigned short* __restrict__ A,
    const unsigned short* __restrict__ Wq, const unsigned short* __restrict__ Wk,
    const unsigned short* __restrict__ Wv,
    const float* __restrict__ bq, const float* __restrict__ bk, const float* __restrict__ bv,
    unsigned short* __restrict__ qo, unsigned short* __restrict__ ko,
    unsigned short* __restrict__ vo) {
  __shared__ alignas(16) unsigned short As[128 * 32];
  __shared__ alignas(16) unsigned short Bs[128 * 32];
  const int z = blockIdx.z;
  const unsigned short* W = (z == 0) ? Wq : (z == 1) ? Wk : Wv;
  const float* bias = (z == 0) ? bq : (z == 1) ? bk : bv;
  const float oscale = (z == 0) ? 0.125f : 1.0f;

  const int m0 = blockIdx.x * 128, n0 = blockIdx.y * 128;
  const int tid = threadIdx.x, lane = tid & 63, wvi = tid >> 6;
  const int wr = wvi >> 1, wc = wvi & 1, quad = lane >> 4, l16 = lane & 15;

  floatx4 zf = {0.f, 0.f, 0.f, 0.f};
  floatx4 acc[4][4];
  for (int i = 0; i < 4; i++)
    for (int j = 0; j < 4; j++) acc[i][j] = zf;

  for (int kk = 0; kk < K_; kk += 32) {
#pragma unroll
    for (int i = 0; i < 2; i++) {
      int cb = wvi * 128 + i * 64;   // wave-uniform chunk base (lds dest = base + lane*16B)
      int c = cb + lane;
      int row = c >> 2, kc = c & 3;
      async16(A + (size_t)(m0 + row) * K_ + kk + kc * 8, As + cb * 8);
      async16(W + (size_t)(n0 + row) * K_ + kk + kc * 8, Bs + cb * 8);
    }
    __syncthreads();
    short8 af[4], bfr[4];
#pragma unroll
    for (int mf = 0; mf < 4; mf++)
      af[mf] = *reinterpret_cast<const short8*>(&As[(wr * 64 + mf * 16 + l16) * 32 + quad * 8]);
#pragma unroll
    for (int nf = 0; nf < 4; nf++)
      bfr[nf] = *reinterpret_cast<const short8*>(&Bs[(wc * 64 + nf * 16 + l16) * 32 + quad * 8]);
#pragma unroll
    for (int mf = 0; mf < 4; mf++)
#pragma unroll
      for (int nf = 0; nf < 4; nf++)
        acc[mf][nf] = __builtin_amdgcn_mfma_f32_16x16x32_bf16(af[mf], bfr[nf], acc[mf][nf], 0, 0, 0);
    __syncthreads();
  }

  unsigned short* outp = (z == 0) ? qo : (z == 1) ? ko : vo;
#pragma unroll
  for (int mf = 0; mf < 4; mf++) {
    int mbase = m0 + wr * 64 + mf * 16 + quad * 4;
    int b = mbase >> 11, s = mbase & 2047;
#pragma unroll
    for (int nf = 0; nf < 4; nf++) {
      int n = n0 + wc * 64 + nf * 16 + l16;
      int h = n >> 6, d = n & 63;
      float bvv = bias[n];
      floatx4 c = acc[mf][nf];
      if (z < 2) {
#pragma unroll
        for (int r = 0; r < 4; r++) {
          float val = (c[r] + bvv) * oscale;
          outp[((size_t)(b * NH_ + h) * S_ + (s + r)) * DH_ + d] = f2bf(val);
        }
      } else {
        ushort4v p;
        p.x = f2bf(c[0] + bvv); p.y = f2bf(c[1] + bvv);
        p.z = f2bf(c[2] + bvv); p.w = f2bf(c[3] + bvv);
        *reinterpret_cast<ushort4v*>(&outp[((size_t)(b * NH_ + h) * DH_ + d) * S_ + s]) = p;
      }
    }
  }
}

// ---------------- dual-softmax flash attention, transposed (no LDS) ----------------
// Sᵀ = K·Qᵀ via swapped MFMA operands: C-tile row = key(quad*4+r), col = q(l16).
// The 16x16 C/D layout == the B-operand layout of K=16 MFMA, so exp(Sᵀ) packs
// in-lane into B-frags for Oᵀ = Vᵀ·P (v_mfma_f32_16x16x16_bf16). No LDS, no
// transpose, no fences. Each lane owns one q-row (q = l16):
//   p_global = e*exp(am_key); p_local = maskbit ? e : 0; denominators are
//   per-lane scalars, reduced across quads (shfl 16,32) once at the end.
__global__ __launch_bounds__(256, 4) void attn_kernel(
    const unsigned short* __restrict__ q,   // [B,NH,S,DH] bf16, pre-scaled by 0.125
    const unsigned short* __restrict__ k,   // [B,NH,S,DH] bf16
    const unsigned short* __restrict__ vt,  // [B,NH,DH,S] bf16
    const float* __restrict__ eam,          // [B,S] = exp(amask)
    const unsigned long long* __restrict__ bm,  // [B,S,S/64] bitmask
    const float* __restrict__ gate,         // [B,NH,S]
    float* __restrict__ out) {              // [B,S,H]
  const int qt = blockIdx.x, h = blockIdx.y, b = blockIdx.z;
  const int tid = threadIdx.x, lane = tid & 63, wvi = tid >> 6;
  const int quad = lane >> 4, l16 = lane & 15;
  const int bh = b * NH_ + h;
  const int q0 = qt * 64 + wvi * 16;  // wave's 16 q-rows; this lane's q = q0+l16

  const unsigned short* qrow = q + ((size_t)bh * S_ + q0 + l16) * DH_;
  short8 qf0 = *reinterpret_cast<const short8*>(qrow + quad * 8);
  short8 qf1 = *reinterpret_cast<const short8*>(qrow + 32 + quad * 8);

  floatx4 zf = {0.f, 0.f, 0.f, 0.f};
  float psg = 0.f, psl = 0.f;
  floatx4 accg[4], accl[4];   // Oᵀ tiles: row d = dtile*16+quad*4+r, col q = l16
#pragma unroll
  for (int i = 0; i < 4; i++) { accg[i] = zf; accl[i] = zf; }

  const unsigned short* kp = k + (size_t)bh * S_ * DH_;
  const unsigned short* vp = vt + (size_t)bh * DH_ * S_;
  const float* eamb = eam + (size_t)b * S_;
  const unsigned long long* bmq = bm + ((size_t)b * S_ + q0 + l16) * (S_ / 64);
  const int kfo = l16 * DH_ + quad * 8;          // + t*16*DH_ + k0*DH_
  const int vfo = l16 * (int)S_ + quad * 4;      // + dtile*16*S_ + t*16 + k0

  for (int kt = 0; kt < S_ / 64; kt++) {
    const int k0 = kt * 64;
    // ---- K loads + QKᵀ (transposed scores) ----
    floatx4 scT[4];
#pragma unroll
    for (int t = 0; t < 4; t++) {
      const unsigned short* kr = kp + (size_t)(k0 + t * 16) * DH_ + kfo;
      short8 kf0 = *reinterpret_cast<const short8*>(kr);
      short8 kf1 = *reinterpret_cast<const short8*>(kr + 32);
      scT[t] = __builtin_amdgcn_mfma_f32_16x16x32_bf16(kf0, qf0, zf, 0, 0, 0);
      scT[t] = __builtin_amdgcn_mfma_f32_16x16x32_bf16(kf1, qf1, scT[t], 0, 0, 0);
    }
    // ---- this lane's 64 mask bits (one 8B load) ----
    unsigned long long w = bmq[kt];
    // ---- softmax on Sᵀ tiles; pack P into B-frags in-lane ----
    int pgf[4][2], plf[4][2];
#pragma unroll
    for (int t = 0; t < 4; t++) {
      float4 ea = *reinterpret_cast<const float4*>(eamb + k0 + t * 16 + quad * 4);
      unsigned m4 = (unsigned)(w >> (t * 16 + quad * 4)) & 0xFu;
      float e0 = __expf(scT[t][0]), e1 = __expf(scT[t][1]);
      float e2 = __expf(scT[t][2]), e3 = __expf(scT[t][3]);
      float g0 = e0 * ea.x, g1 = e1 * ea.y, g2 = e2 * ea.z, g3 = e3 * ea.w;
      psg += (g0 + g1) + (g2 + g3);
      float l0 = (m4 & 1u) ? e0 : 0.f;
      float l1 = (m4 & 2u) ? e1 : 0.f;
      float l2 = (m4 & 4u) ? e2 : 0.f;
      float l3 = (m4 & 8u) ? e3 : 0.f;
      psl += (l0 + l1) + (l2 + l3);
      pgf[t][0] = pack2bf(g0, g1); pgf[t][1] = pack2bf(g2, g3);
      plf[t][0] = pack2bf(l0, l1); plf[t][1] = pack2bf(l2, l3);
    }
    // ---- PV: Oᵀ += Vᵀ·P, K=16 MFMAs, V A-frags straight from vt ----
#pragma unroll
    for (int d = 0; d < 4; d++) {
      const unsigned short* vr = vp + (size_t)d * 16 * S_ + vfo + k0;
#pragma unroll
      for (int t = 0; t < 4; t++) {
        short4v vf = *reinterpret_cast<const short4v*>(vr + t * 16);
        short4v pg = *reinterpret_cast<const short4v*>(&pgf[t][0]);
        short4v pl = *reinterpret_cast<const short4v*>(&plf[t][0]);
        accg[d] = __builtin_amdgcn_mfma_f32_16x16x16bf16_1k(vf, pg, accg[d], 0, 0, 0);
        accl[d] = __builtin_amdgcn_mfma_f32_16x16x16bf16_1k(vf, pl, accl[d], 0, 0, 0);
      }
    }
  }

  // ---- epilogue: quad-reduce denominators, gate-combine, float4 stores ----
  float lgf = psg;
  lgf += __shfl_xor(lgf, 16, 64);
  lgf += __shfl_xor(lgf, 32, 64);
  float llf = psl;
  llf += __shfl_xor(llf, 16, 64);
  llf += __shfl_xor(llf, 32, 64);
  const int s = q0 + l16;
  const float g = gate[(size_t)bh * S_ + s];
  const float cg = (1.f - g) / lgf, cl = g / llf;
  float* orow = out + ((size_t)b * S_ + s) * H_ + h * DH_ + quad * 4;
#pragma unroll
  for (int d = 0; d < 4; d++) {
    float4 o;
    o.x = cl * accl[d][0] + cg * accg[d][0];
    o.y = cl * accl[d][1] + cg * accg[d][1];
    o.z = cl * accl[d][2] + cg * accg[d][2];
    o.w = cl * accl[d][3] + cg * accg[d][3];
    *reinterpret_cast<float4*>(orow + d * 16) = o;
  }
}

extern "C" void kernel_launch(void* const* d_in, const int* in_sizes, int n_in,
                              void* d_out, int out_size, void* d_ws, size_t ws_size,
                              hipStream_t stream) {
  (void)in_sizes; (void)n_in; (void)out_size; (void)ws_size;
  const float* hs = (const float*)d_in[0];
  const float* am = (const float*)d_in[1];
  const int* lm = (const int*)d_in[2];
  const float* gate = (const float*)d_in[3];
  const float* Wq = (const float*)d_in[4];
  const float* bq = (const float*)d_in[5];
  const float* Wk = (const float*)d_in[6];
  const float* bk = (const float*)d_in[7];
  const float* Wv = (const float*)d_in[8];
  const float* bv = (const float*)d_in[9];
  float* out = (float*)d_out;

  unsigned short* ws = (unsigned short*)d_ws;
  unsigned short* hbf = ws;                  // 4,194,304 elems
  unsigned short* wqb = hbf + 4194304;       // 1,048,576
  unsigned short* wkb = wqb + 1048576;
  unsigned short* wvb = wkb + 1048576;
  unsigned short* qb = wvb + 1048576;        // 4,194,304
  unsigned short* kb = qb + 4194304;
  unsigned short* vtb = kb + 4194304;
  unsigned long long* bmp = (unsigned long long*)(vtb + 4194304);  // 1 MB
  float* eamp = (float*)(bmp + 131072);      // 4096 floats

  cvt_bf16<<<4096, 256, 0, stream>>>(hs, hbf, 4194304);
  cvt_bf16<<<1024, 256, 0, stream>>>(Wq, wqb, 1048576);
  cvt_bf16<<<1024, 256, 0, stream>>>(Wk, wkb, 1048576);
  cvt_bf16<<<1024, 256, 0, stream>>>(Wv, wvb, 1048576);
  build_bitmask<<<32768, 256, 0, stream>>>(lm, bmp);
  build_eam<<<16, 256, 0, stream>>>(am, eamp);
  gemm_qkv<<<dim3(32, 8, 3), 256, 0, stream>>>(hbf, wqb, wkb, wvb, bq, bk, bv, qb, kb, vtb);
  attn_kernel<<<dim3(32, 16, 2), 256, 0, stream>>>(qb, kb, vtb, eamp, bmp, gate, out);
}

// Round 6
// 291.924 us; speedup vs baseline: 1.8560x; 1.8560x over previous
//
#include <hip/hip_runtime.h>
#include <cstdint>
#include <cstddef>

typedef short short8 __attribute__((ext_vector_type(8)));
typedef short short4v __attribute__((ext_vector_type(4)));
typedef float floatx4 __attribute__((ext_vector_type(4)));
typedef unsigned short ushort4v __attribute__((ext_vector_type(4)));

constexpr int B_ = 2, S_ = 2048, H_ = 1024, NH_ = 16, DH_ = 64;
constexpr int M_ = B_ * S_;   // 4096
constexpr int K_ = H_;        // 1024

__device__ __forceinline__ unsigned short f2bf(float f) {
  unsigned u = __float_as_uint(f);
  u += 0x7fffu + ((u >> 16) & 1u);   // RNE
  return (unsigned short)(u >> 16);
}

// pack two floats to bf16x2 (round-half-up; bias cancels in p/sum(p))
__device__ __forceinline__ unsigned pack2bf(float a, float b) {
  unsigned ua = (__float_as_uint(a) + 0x8000u) >> 16;
  unsigned ub = (__float_as_uint(b) + 0x8000u) & 0xffff0000u;
  return ua | ub;
}

// ---------------- fp32 -> bf16 conversion ----------------
__global__ __launch_bounds__(256) void cvt_bf16(const float* __restrict__ in,
                                                unsigned short* __restrict__ out, int n) {
  int i = (blockIdx.x * blockDim.x + threadIdx.x) * 4;
  if (i >= n) return;
  float4 v = *reinterpret_cast<const float4*>(in + i);
  ushort4v o;
  o.x = f2bf(v.x); o.y = f2bf(v.y); o.z = f2bf(v.z); o.w = f2bf(v.w);
  *reinterpret_cast<ushort4v*>(out + i) = o;
}

// ---------------- local mask -> bitmask (1 bit/key) ----------------
__global__ __launch_bounds__(256) void build_bitmask(const int* __restrict__ lm,
                                                     unsigned long long* __restrict__ bm) {
  int word = blockIdx.x * 4 + (threadIdx.x >> 6);
  int lane = threadIdx.x & 63;
  unsigned long long bits = __ballot(lm[(size_t)word * 64 + lane] != 0);
  if (lane == 0) bm[word] = bits;
}

// ---------------- exp(amask) table [B,S] ----------------
__global__ __launch_bounds__(256) void build_eam(const float* __restrict__ am,
                                                 float* __restrict__ ea) {
  int i = blockIdx.x * 256 + threadIdx.x;
  ea[i] = __expf(am[i]);
}

// ---------------- async global->LDS 16B ----------------
typedef __attribute__((address_space(1))) const void gvoid;
typedef __attribute__((address_space(3))) void lvoid;
__device__ __forceinline__ void async16(const unsigned short* gp, unsigned short* lp) {
  __builtin_amdgcn_global_load_lds((gvoid*)gp, (lvoid*)lp, 16, 0, 0);
}

// ---------------- QKV projection GEMM (unchanged, verified) ----------------
__global__ __launch_bounds__(256) void gemm_qkv(
    const unsigned short* __restrict__ A,
    const unsigned short* __restrict__ Wq, const unsigned short* __restrict__ Wk,
    const unsigned short* __restrict__ Wv,
    const float* __restrict__ bq, const float* __restrict__ bk, const float* __restrict__ bv,
    unsigned short* __restrict__ qo, unsigned short* __restrict__ ko,
    unsigned short* __restrict__ vo) {
  __shared__ alignas(16) unsigned short As[128 * 32];
  __shared__ alignas(16) unsigned short Bs[128 * 32];
  const int z = blockIdx.z;
  const unsigned short* W = (z == 0) ? Wq : (z == 1) ? Wk : Wv;
  const float* bias = (z == 0) ? bq : (z == 1) ? bk : bv;
  const float oscale = (z == 0) ? 0.125f : 1.0f;

  const int m0 = blockIdx.x * 128, n0 = blockIdx.y * 128;
  const int tid = threadIdx.x, lane = tid & 63, wvi = tid >> 6;
  const int wr = wvi >> 1, wc = wvi & 1, quad = lane >> 4, l16 = lane & 15;

  floatx4 zf = {0.f, 0.f, 0.f, 0.f};
  floatx4 acc[4][4];
  for (int i = 0; i < 4; i++)
    for (int j = 0; j < 4; j++) acc[i][j] = zf;

  for (int kk = 0; kk < K_; kk += 32) {
#pragma unroll
    for (int i = 0; i < 2; i++) {
      int cb = wvi * 128 + i * 64;   // wave-uniform chunk base (lds dest = base + lane*16B)
      int c = cb + lane;
      int row = c >> 2, kc = c & 3;
      async16(A + (size_t)(m0 + row) * K_ + kk + kc * 8, As + cb * 8);
      async16(W + (size_t)(n0 + row) * K_ + kk + kc * 8, Bs + cb * 8);
    }
    __syncthreads();
    short8 af[4], bfr[4];
#pragma unroll
    for (int mf = 0; mf < 4; mf++)
      af[mf] = *reinterpret_cast<const short8*>(&As[(wr * 64 + mf * 16 + l16) * 32 + quad * 8]);
#pragma unroll
    for (int nf = 0; nf < 4; nf++)
      bfr[nf] = *reinterpret_cast<const short8*>(&Bs[(wc * 64 + nf * 16 + l16) * 32 + quad * 8]);
#pragma unroll
    for (int mf = 0; mf < 4; mf++)
#pragma unroll
      for (int nf = 0; nf < 4; nf++)
        acc[mf][nf] = __builtin_amdgcn_mfma_f32_16x16x32_bf16(af[mf], bfr[nf], acc[mf][nf], 0, 0, 0);
    __syncthreads();
  }

  unsigned short* outp = (z == 0) ? qo : (z == 1) ? ko : vo;
#pragma unroll
  for (int mf = 0; mf < 4; mf++) {
    int mbase = m0 + wr * 64 + mf * 16 + quad * 4;
    int b = mbase >> 11, s = mbase & 2047;
#pragma unroll
    for (int nf = 0; nf < 4; nf++) {
      int n = n0 + wc * 64 + nf * 16 + l16;
      int h = n >> 6, d = n & 63;
      float bvv = bias[n];
      floatx4 c = acc[mf][nf];
      if (z < 2) {
#pragma unroll
        for (int r = 0; r < 4; r++) {
          float val = (c[r] + bvv) * oscale;
          outp[((size_t)(b * NH_ + h) * S_ + (s + r)) * DH_ + d] = f2bf(val);
        }
      } else {
        ushort4v p;
        p.x = f2bf(c[0] + bvv); p.y = f2bf(c[1] + bvv);
        p.z = f2bf(c[2] + bvv); p.w = f2bf(c[3] + bvv);
        *reinterpret_cast<ushort4v*>(&outp[((size_t)(b * NH_ + h) * DH_ + d) * S_ + s]) = p;
      }
    }
  }
}

// ------- dual-softmax flash attention: transposed scores + LDS K/V staging -------
// Sᵀ = K·Qᵀ (swapped MFMA operands): C row = key, col = q(l16). The 16x16 C/D
// layout == B-operand layout of the K=16 MFMA, so exp(Sᵀ) packs in-lane into
// B-frags for Oᵀ = Vᵀ·P. P never leaves registers.
// K/V tiles (8KB each) are SHARED by all 4 waves -> cooperative staging into
// LDS, double-buffered: prefetch tile kt+1 into VGPRs while computing kt from
// LDS, write at iteration end. All global loads per iter are 4 batched
// dwordx4/thread with no dependent use until the next barrier (full MLP);
// in-loop reads are LDS (~120cyc). Row stride 72 elems (144B): 16B-aligned
// b128 rows; banks spread 4*l16+4*quad -> ~2-way (free, m136).
constexpr int KVP = 72;

__global__ __launch_bounds__(256, 4) void attn_kernel(
    const unsigned short* __restrict__ q,   // [B,NH,S,DH] bf16, pre-scaled by 0.125
    const unsigned short* __restrict__ k,   // [B,NH,S,DH] bf16
    const unsigned short* __restrict__ vt,  // [B,NH,DH,S] bf16
    const float* __restrict__ eam,          // [B,S] = exp(amask)
    const unsigned long long* __restrict__ bm,  // [B,S,S/64] bitmask
    const float* __restrict__ gate,         // [B,NH,S]
    float* __restrict__ out) {              // [B,S,H]
  __shared__ alignas(16) unsigned short Ks[2][64 * KVP];
  __shared__ alignas(16) unsigned short Vs[2][64 * KVP];

  const int qt = blockIdx.x, h = blockIdx.y, b = blockIdx.z;
  const int tid = threadIdx.x, lane = tid & 63, wvi = tid >> 6;
  const int quad = lane >> 4, l16 = lane & 15;
  const int bh = b * NH_ + h;
  const int q0 = qt * 64 + wvi * 16;  // wave's 16 q-rows; this lane's q = q0+l16

  const unsigned short* qrow = q + ((size_t)bh * S_ + q0 + l16) * DH_;
  short8 qf0 = *reinterpret_cast<const short8*>(qrow + quad * 8);
  short8 qf1 = *reinterpret_cast<const short8*>(qrow + 32 + quad * 8);

  floatx4 zf = {0.f, 0.f, 0.f, 0.f};
  float psg = 0.f, psl = 0.f;
  floatx4 accg[4], accl[4];   // Oᵀ tiles: row d = dtile*16+quad*4+r, col q = l16
#pragma unroll
  for (int i = 0; i < 4; i++) { accg[i] = zf; accl[i] = zf; }

  const unsigned short* kp = k + (size_t)bh * S_ * DH_;
  const unsigned short* vp = vt + (size_t)bh * DH_ * S_;
  const float* eamb = eam + (size_t)b * S_;
  const unsigned long long* bmq = bm + ((size_t)b * S_ + q0 + l16) * (S_ / 64);

  // staging geometry: thread -> row tid>>2, 32B column chunk (tid&3)*16 elems
  const int srow = tid >> 2, scol = (tid & 3) * 16;
  const unsigned short* kgb = kp + srow * DH_ + scol;      // + kt*64*DH_
  const unsigned short* vgb = vp + (size_t)srow * S_ + scol;  // + kt*64
  const int lds_off = srow * KVP + scol;

  // prefetch tile 0 and stage into buffer 0
  uint4 pk0 = *reinterpret_cast<const uint4*>(kgb);
  uint4 pk1 = *reinterpret_cast<const uint4*>(kgb + 8);
  uint4 pv0 = *reinterpret_cast<const uint4*>(vgb);
  uint4 pv1 = *reinterpret_cast<const uint4*>(vgb + 8);
  *reinterpret_cast<uint4*>(&Ks[0][lds_off]) = pk0;
  *reinterpret_cast<uint4*>(&Ks[0][lds_off + 8]) = pk1;
  *reinterpret_cast<uint4*>(&Vs[0][lds_off]) = pv0;
  *reinterpret_cast<uint4*>(&Vs[0][lds_off + 8]) = pv1;

  for (int kt = 0; kt < S_ / 64; kt++) {
    __syncthreads();  // buf[kt&1] staged and visible
    const int k0 = kt * 64;
    // ---- prefetch tile kt+1 into regs (wraps; no use until after barrier) ----
    {
      const int ktn = (kt + 1) & 31;
      const unsigned short* kg = kgb + ktn * 64 * DH_;
      const unsigned short* vg = vgb + ktn * 64;
      pk0 = *reinterpret_cast<const uint4*>(kg);
      pk1 = *reinterpret_cast<const uint4*>(kg + 8);
      pv0 = *reinterpret_cast<const uint4*>(vg);
      pv1 = *reinterpret_cast<const uint4*>(vg + 8);
    }
    // ---- this lane's mask bits + eam (independent, issued early) ----
    unsigned long long w = bmq[kt];
    float4 ea[4];
#pragma unroll
    for (int t = 0; t < 4; t++)
      ea[t] = *reinterpret_cast<const float4*>(eamb + k0 + t * 16 + quad * 4);

    const unsigned short* Kc = &Ks[kt & 1][0];
    const unsigned short* Vc = &Vs[kt & 1][0];
    // ---- QKᵀ from LDS K ----
    floatx4 scT[4];
#pragma unroll
    for (int t = 0; t < 4; t++) {
      const unsigned short* kr = Kc + (t * 16 + l16) * KVP + quad * 8;
      short8 kf0 = *reinterpret_cast<const short8*>(kr);
      short8 kf1 = *reinterpret_cast<const short8*>(kr + 32);
      scT[t] = __builtin_amdgcn_mfma_f32_16x16x32_bf16(kf0, qf0, zf, 0, 0, 0);
      scT[t] = __builtin_amdgcn_mfma_f32_16x16x32_bf16(kf1, qf1, scT[t], 0, 0, 0);
    }
    // ---- softmax on Sᵀ tiles; pack P into B-frags in-lane ----
    int pgf[4][2], plf[4][2];
#pragma unroll
    for (int t = 0; t < 4; t++) {
      unsigned m4 = (unsigned)(w >> (t * 16 + quad * 4)) & 0xFu;
      float e0 = __expf(scT[t][0]), e1 = __expf(scT[t][1]);
      float e2 = __expf(scT[t][2]), e3 = __expf(scT[t][3]);
      float g0 = e0 * ea[t].x, g1 = e1 * ea[t].y, g2 = e2 * ea[t].z, g3 = e3 * ea[t].w;
      psg += (g0 + g1) + (g2 + g3);
      float l0 = (m4 & 1u) ? e0 : 0.f;
      float l1 = (m4 & 2u) ? e1 : 0.f;
      float l2 = (m4 & 4u) ? e2 : 0.f;
      float l3 = (m4 & 8u) ? e3 : 0.f;
      psl += (l0 + l1) + (l2 + l3);
      pgf[t][0] = pack2bf(g0, g1); pgf[t][1] = pack2bf(g2, g3);
      plf[t][0] = pack2bf(l0, l1); plf[t][1] = pack2bf(l2, l3);
    }
    // ---- PV from LDS Vᵀ: Oᵀ += Vᵀ·P (K=16 MFMAs) ----
#pragma unroll
    for (int d = 0; d < 4; d++) {
      const unsigned short* vr = Vc + (d * 16 + l16) * KVP + quad * 4;
#pragma unroll
      for (int t = 0; t < 4; t++) {
        short4v vf = *reinterpret_cast<const short4v*>(vr + t * 16);
        short4v pg = *reinterpret_cast<const short4v*>(&pgf[t][0]);
        short4v pl = *reinterpret_cast<const short4v*>(&plf[t][0]);
        accg[d] = __builtin_amdgcn_mfma_f32_16x16x16bf16_1k(vf, pg, accg[d], 0, 0, 0);
        accl[d] = __builtin_amdgcn_mfma_f32_16x16x16bf16_1k(vf, pl, accl[d], 0, 0, 0);
      }
    }
    __syncthreads();  // all waves done reading buf[(kt+1)&1] (two iters ago)
    // ---- stage prefetched tile kt+1 ----
    {
      const int bn = (kt + 1) & 1;
      *reinterpret_cast<uint4*>(&Ks[bn][lds_off]) = pk0;
      *reinterpret_cast<uint4*>(&Ks[bn][lds_off + 8]) = pk1;
      *reinterpret_cast<uint4*>(&Vs[bn][lds_off]) = pv0;
      *reinterpret_cast<uint4*>(&Vs[bn][lds_off + 8]) = pv1;
    }
  }

  // ---- epilogue: quad-reduce denominators, gate-combine, float4 stores ----
  float lgf = psg;
  lgf += __shfl_xor(lgf, 16, 64);
  lgf += __shfl_xor(lgf, 32, 64);
  float llf = psl;
  llf += __shfl_xor(llf, 16, 64);
  llf += __shfl_xor(llf, 32, 64);
  const int s = q0 + l16;
  const float g = gate[(size_t)bh * S_ + s];
  const float cg = (1.f - g) / lgf, cl = g / llf;
  float* orow = out + ((size_t)b * S_ + s) * H_ + h * DH_ + quad * 4;
#pragma unroll
  for (int d = 0; d < 4; d++) {
    float4 o;
    o.x = cl * accl[d][0] + cg * accg[d][0];
    o.y = cl * accl[d][1] + cg * accg[d][1];
    o.z = cl * accl[d][2] + cg * accg[d][2];
    o.w = cl * accl[d][3] + cg * accg[d][3];
    *reinterpret_cast<float4*>(orow + d * 16) = o;
  }
}

extern "C" void kernel_launch(void* const* d_in, const int* in_sizes, int n_in,
                              void* d_out, int out_size, void* d_ws, size_t ws_size,
                              hipStream_t stream) {
  (void)in_sizes; (void)n_in; (void)out_size; (void)ws_size;
  const float* hs = (const float*)d_in[0];
  const float* am = (const float*)d_in[1];
  const int* lm = (const int*)d_in[2];
  const float* gate = (const float*)d_in[3];
  const float* Wq = (const float*)d_in[4];
  const float* bq = (const float*)d_in[5];
  const float* Wk = (const float*)d_in[6];
  const float* bk = (const float*)d_in[7];
  const float* Wv = (const float*)d_in[8];
  const float* bv = (const float*)d_in[9];
  float* out = (float*)d_out;

  unsigned short* ws = (unsigned short*)d_ws;
  unsigned short* hbf = ws;                  // 4,194,304 elems
  unsigned short* wqb = hbf + 4194304;       // 1,048,576
  unsigned short* wkb = wqb + 1048576;
  unsigned short* wvb = wkb + 1048576;
  unsigned short* qb = wvb + 1048576;        // 4,194,304
  unsigned short* kb = qb + 4194304;
  unsigned short* vtb = kb + 4194304;
  unsigned long long* bmp = (unsigned long long*)(vtb + 4194304);  // 1 MB
  float* eamp = (float*)(bmp + 131072);      // 4096 floats

  cvt_bf16<<<4096, 256, 0, stream>>>(hs, hbf, 4194304);
  cvt_bf16<<<1024, 256, 0, stream>>>(Wq, wqb, 1048576);
  cvt_bf16<<<1024, 256, 0, stream>>>(Wk, wkb, 1048576);
  cvt_bf16<<<1024, 256, 0, stream>>>(Wv, wvb, 1048576);
  build_bitmask<<<32768, 256, 0, stream>>>(lm, bmp);
  build_eam<<<16, 256, 0, stream>>>(am, eamp);
  gemm_qkv<<<dim3(32, 8, 3), 256, 0, stream>>>(hbf, wqb, wkb, wvb, bq, bk, bv, qb, kb, vtb);
  attn_kernel<<<dim3(32, 16, 2), 256, 0, stream>>>(qb, kb, vtb, eamp, bmp, gate, out);
}